// Round 3
// baseline (167.778 us; speedup 1.0000x reference)
//
#include <hip/hip_runtime.h>

#define IMG_H 512
#define IMG_W 512
#define NCLS  21
#define HWC   (IMG_H * IMG_W)

// 1/ln(501)
#define INV_LOG_MAXR 0.16085936f

// ---------------- union-find ----------------
// Lock-free union-find with union-by-min + path halving (ECL-CC style).
// Reads go through volatile (L2-coherent, bypass L1) so remote CUs'
// atomicCAS updates are always observed; CAS return values drive progress.
// Termination: parent values strictly decrease along chains (union-by-min,
// path halving writes ancestors which always have smaller flat index).

__device__ __forceinline__ int find_root(int* parent, int x) {
    volatile int* vp = (volatile int*)parent;
    int p = vp[x];
    while (p != x) {
        int gp = vp[p];
        if (gp != p) parent[x] = gp;  // path halving: gp is an ancestor -> race-safe
        x = p;
        p = vp[x];
        if (p == x) return x;
    }
    return x;
}

__device__ __forceinline__ void unite(int* parent, int a, int b) {
    while (true) {
        a = find_root(parent, a);
        b = find_root(parent, b);
        if (a == b) return;
        if (a < b) {
            int old = atomicCAS(&parent[b], b, a);
            if (old == b) return;
            b = old;   // progress driven by coherent CAS return value
        } else {
            int old = atomicCAS(&parent[a], a, b);
            if (old == a) return;
            a = old;
        }
    }
}

// ---------------- kernels ----------------

__global__ __launch_bounds__(256) void init_kernel(int* __restrict__ parent,
                                                   int* __restrict__ counts,
                                                   float* __restrict__ acc,
                                                   int n) {
    int i = blockIdx.x * blockDim.x + threadIdx.x;
    if (i < n) {
        parent[i] = i;
        counts[i] = 0;
    }
    if (i == 0) *acc = 0.0f;
}

__global__ __launch_bounds__(256) void merge_kernel(const int* __restrict__ tgt,
                                                    int* __restrict__ parent,
                                                    int n) {
    int i = blockIdx.x * blockDim.x + threadIdx.x;
    if (i >= n) return;
    int t = tgt[i];
    if (t <= 0) return;                 // class 0 = background, excluded
    int w = i & (IMG_W - 1);
    int h = (i >> 9) & (IMG_H - 1);
    if (w + 1 < IMG_W && tgt[i + 1] == t)     unite(parent, i, i + 1);
    if (h + 1 < IMG_H && tgt[i + IMG_W] == t) unite(parent, i, i + IMG_W);
}

__global__ __launch_bounds__(256) void count_kernel(const int* __restrict__ tgt,
                                                    int* __restrict__ parent,
                                                    int* __restrict__ counts,
                                                    int n) {
    int i = blockIdx.x * blockDim.x + threadIdx.x;
    if (i >= n) return;
    if (tgt[i] > 0) {
        int r = find_root(parent, i);
        parent[i] = r;                  // full compression so CE kernel reads root directly
        atomicAdd(&counts[r], 1);
    }
}

__global__ __launch_bounds__(256) void ce_weight_kernel(const float* __restrict__ logits,
                                                        const int* __restrict__ tgt,
                                                        const int* __restrict__ parent,
                                                        const int* __restrict__ counts,
                                                        float* __restrict__ acc,
                                                        int n_pix) {
    int gid  = blockIdx.x * blockDim.x + threadIdx.x;
    int base = gid * 4;
    float local = 0.0f;

    if (base < n_pix) {
        int b   = base / HWC;
        int rem = base - b * HWC;
        const float* lp = logits + (size_t)b * NCLS * HWC + rem;

        // load all 21 classes x 4 pixels into registers (84 VGPRs, static indexing)
        float xs[NCLS][4];
#pragma unroll
        for (int c = 0; c < NCLS; ++c) {
            float4 v = *reinterpret_cast<const float4*>(lp + (size_t)c * HWC);
            xs[c][0] = v.x; xs[c][1] = v.y; xs[c][2] = v.z; xs[c][3] = v.w;
        }

        float m[4];
#pragma unroll
        for (int j = 0; j < 4; ++j) m[j] = xs[0][j];
#pragma unroll
        for (int c = 1; c < NCLS; ++c)
#pragma unroll
            for (int j = 0; j < 4; ++j) m[j] = fmaxf(m[j], xs[c][j]);

        float s[4] = {0.f, 0.f, 0.f, 0.f};
#pragma unroll
        for (int c = 0; c < NCLS; ++c)
#pragma unroll
            for (int j = 0; j < 4; ++j) s[j] += __expf(xs[c][j] - m[j]);

        int4 t4 = *reinterpret_cast<const int4*>(tgt + base);
        int tj[4] = {t4.x, t4.y, t4.z, t4.w};

        float xt[4];
#pragma unroll
        for (int j = 0; j < 4; ++j) xt[j] = xs[0][j];
#pragma unroll
        for (int c = 1; c < NCLS; ++c)
#pragma unroll
            for (int j = 0; j < 4; ++j)
                if (tj[j] == c) xt[j] = xs[c][j];

#pragma unroll
        for (int j = 0; j < 4; ++j) {
            float ce = m[j] + __logf(s[j]) - xt[j];
            float wgt = 1.0f;
            if (tj[j] > 0) {
                int r = parent[base + j];        // already fully compressed
                float size = (float)counts[r];
                if (size < 500.0f)
                    wgt = 3.0f * __logf(size + 1.0f) * INV_LOG_MAXR;
            }
            local += ce * wgt;
        }
    }

    // block reduction: wave64 shuffle, then 4 partials through LDS
#pragma unroll
    for (int off = 32; off > 0; off >>= 1)
        local += __shfl_down(local, off, 64);

    __shared__ float red[4];
    int lane = threadIdx.x & 63;
    int wid  = threadIdx.x >> 6;
    if (lane == 0) red[wid] = local;
    __syncthreads();
    if (threadIdx.x == 0)
        atomicAdd(acc, red[0] + red[1] + red[2] + red[3]);
}

__global__ void finalize_kernel(const float* __restrict__ acc,
                                float* __restrict__ out,
                                float inv_n) {
    if (threadIdx.x == 0 && blockIdx.x == 0)
        out[0] = acc[0] * inv_n;
}

// ---------------- launch ----------------

extern "C" void kernel_launch(void* const* d_in, const int* in_sizes, int n_in,
                              void* d_out, int out_size, void* d_ws, size_t ws_size,
                              hipStream_t stream) {
    const float* logits = (const float*)d_in[0];
    const int*   tgt    = (const int*)d_in[1];
    float*       out    = (float*)d_out;

    int n_pix = in_sizes[1];               // B*H*W = 4*512*512 = 1048576

    int*   parent = (int*)d_ws;
    int*   counts = parent + n_pix;
    float* acc    = (float*)(counts + n_pix);

    int blocksN  = (n_pix + 255) / 256;
    int blocksCE = (n_pix / 4 + 255) / 256;

    hipLaunchKernelGGL(init_kernel,  dim3(blocksN),  dim3(256), 0, stream, parent, counts, acc, n_pix);
    hipLaunchKernelGGL(merge_kernel, dim3(blocksN),  dim3(256), 0, stream, tgt, parent, n_pix);
    hipLaunchKernelGGL(count_kernel, dim3(blocksN),  dim3(256), 0, stream, tgt, parent, counts, n_pix);
    hipLaunchKernelGGL(ce_weight_kernel, dim3(blocksCE), dim3(256), 0, stream,
                       logits, tgt, parent, counts, acc, n_pix);
    hipLaunchKernelGGL(finalize_kernel, dim3(1), dim3(64), 0, stream, acc, out, 1.0f / (float)n_pix);
}